// Round 1
// 259.595 us; speedup vs baseline: 1.0105x; 1.0105x over previous
//
#include <hip/hip_runtime.h>

typedef unsigned int u32;
typedef float f32x4 __attribute__((ext_vector_type(4)));

#define BB 8
#define SS 2048
#define KK 16
#define RR 16
#define DIN 2048
#define DOUT 2048

// ---------------------------------------------------------------------------
// Kernel 1: mix the banks (all fp32).
//   Am[b][r][i] = sum_k alpha[b][k] * A_bank[k][r][i]
//   Bm[b][o][r] = sum_k alpha[b][k] * B_bank[k][o][r]
// Unchanged from previous round (reads ~32 MB of L2-resident banks, ~5 us).
// ---------------------------------------------------------------------------
__global__ void __launch_bounds__(256) mix_kernel(
    const float* __restrict__ alpha,
    const float* __restrict__ A_bank,
    const float* __restrict__ B_bank,
    float* __restrict__ Am,
    float* __restrict__ Bm)
{
    int t = blockIdx.x * 256 + threadIdx.x;
    const int half = BB * RR * DIN;  // 262144
    if (t < half) {
        // t = (b*RR + r)*DIN + i   (i fastest -> coalesced)
        int i = t & (DIN - 1);
        int r = (t >> 11) & (RR - 1);
        int b = t >> 15;
        float acc = 0.f;
#pragma unroll
        for (int k = 0; k < KK; ++k)
            acc += alpha[b * KK + k] * A_bank[(k * RR + r) * DIN + i];
        Am[t] = acc;
    } else {
        int u = t - half;
        // u = (b*DOUT + o)*RR + r  (r fastest -> coalesced)
        int r = u & (RR - 1);
        int o = (u >> 4) & (DOUT - 1);
        int b = u >> 15;
        float acc = 0.f;
#pragma unroll
        for (int k = 0; k < KK; ++k)
            acc += alpha[b * KK + k] * B_bank[(k * DOUT + o) * RR + r];
        Bm[u] = acc;
    }
}

// ---------------------------------------------------------------------------
// Kernel 2 (FUSED z + delta): one block owns (b, 16 s-rows).
//
// Phase 1 (verified z-tile structure from previous round): wave owns 4 s rows,
// lanes span i (coalesced float4, nontemporal: h is read-once, keep Am/Bm in
// L2). Tree reduction with payload halving; lane l ends with z value index
// l = j*16 + r for its wave's rows. z-tile (16x16 = 1 KB) -> LDS, NOT global.
//
// Phase 2: after one barrier, 256 threads produce the 16 x 2048 delta tile.
// Thread owns 4 contiguous o per o-chunk (2 chunks); Bm rows in registers;
// z rows are wave-uniform LDS broadcasts (conflict-free). Nontemporal stores.
//
// Why fused: read-heavy phase-1 blocks and write-heavy phase-2 blocks
// interleave on each CU (3 resident), overlapping HBM read and write BW that
// the 3-kernel chain serialized; kills the z global round-trip and a launch.
// Grid: (S/16, B) = (128, 8) = 1024 blocks, 3 blocks/CU resident (~165 VGPR).
// ---------------------------------------------------------------------------
__global__ void __launch_bounds__(256, 3) fused_kernel(
    const float* __restrict__ h,
    const float* __restrict__ Am,
    const float* __restrict__ Bm,
    float* __restrict__ out)
{
    __shared__ float zt[16 * 16];   // z tile: zt[s_local*16 + r]

    int b = blockIdx.y;
    int wid = threadIdx.x >> 6;
    int lane = threadIdx.x & 63;
    int s0 = blockIdx.x * 16;             // tile's first s row
    int sw = s0 + wid * 4;                // this wave's first s row

    const float* hb = h + (size_t)b * SS * DIN + (size_t)sw * DIN;
    const float* Ab = Am + (size_t)b * RR * DIN;

    float a[64];
#pragma unroll
    for (int v = 0; v < 64; ++v) a[v] = 0.f;

#pragma unroll 1
    for (int t = 0; t < 8; ++t) {
        int i0 = t * 256 + lane * 4;
        f32x4 hv0 = __builtin_nontemporal_load((const f32x4*)(hb + i0));
        f32x4 hv1 = __builtin_nontemporal_load((const f32x4*)(hb + DIN + i0));
        f32x4 hv2 = __builtin_nontemporal_load((const f32x4*)(hb + 2 * DIN + i0));
        f32x4 hv3 = __builtin_nontemporal_load((const f32x4*)(hb + 3 * DIN + i0));
#pragma unroll
        for (int r = 0; r < 16; ++r) {
            f32x4 av = *(const f32x4*)(Ab + r * DIN + i0);
            a[0 * 16 + r] += hv0.x * av.x + hv0.y * av.y + hv0.z * av.z + hv0.w * av.w;
            a[1 * 16 + r] += hv1.x * av.x + hv1.y * av.y + hv1.z * av.z + hv1.w * av.w;
            a[2 * 16 + r] += hv2.x * av.x + hv2.y * av.y + hv2.z * av.z + hv2.w * av.w;
            a[3 * 16 + r] += hv3.x * av.x + hv3.y * av.y + hv3.z * av.z + hv3.w * av.w;
        }
    }

    // Cross-lane tree reduction, payload halving each step (63 shfl total).
    // lane l ends holding sum over all i of value index l (= j*16 + r).
#pragma unroll
    for (int off = 32; off >= 1; off >>= 1) {
        bool up = (lane & off) != 0;
#pragma unroll
        for (int v = 0; v < off; ++v) {
            float send = up ? a[v] : a[v + off];
            float keep = up ? a[v + off] : a[v];
            a[v] = keep + __shfl_xor(send, off, 64);
        }
    }
    // lane l -> zt[(wid*4 + l/16)*16 + l%16] = zt[wid*64 + l]  (contiguous)
    zt[wid * 64 + lane] = a[0];
    __syncthreads();

    // ------------------- Phase 2: delta tile from LDS z ---------------------
    float* op = out + ((size_t)b * SS + s0) * DOUT;

#pragma unroll 1
    for (int oc = 0; oc < 2; ++oc) {
        int o0 = oc * 1024 + threadIdx.x * 4;
        const float* wp = Bm + ((size_t)b * DOUT + o0) * RR;  // 64 contiguous
        float w[4][16];
#pragma unroll
        for (int j = 0; j < 4; ++j) {
#pragma unroll
            for (int q = 0; q < 4; ++q) {
                f32x4 p = *(const f32x4*)(wp + j * RR + q * 4);
                w[j][q * 4 + 0] = p.x; w[j][q * 4 + 1] = p.y;
                w[j][q * 4 + 2] = p.z; w[j][q * 4 + 3] = p.w;
            }
        }
#pragma unroll 4
        for (int s = 0; s < 16; ++s) {
            // wave-uniform LDS reads -> broadcast, no bank conflicts
            float zz[16];
#pragma unroll
            for (int q = 0; q < 4; ++q) {
                f32x4 zv = *(const f32x4*)(zt + s * 16 + q * 4);
                zz[q * 4 + 0] = zv.x; zz[q * 4 + 1] = zv.y;
                zz[q * 4 + 2] = zv.z; zz[q * 4 + 3] = zv.w;
            }
            float rj[4];
#pragma unroll
            for (int j = 0; j < 4; ++j) {
                float acc = 0.f;
#pragma unroll
                for (int r = 0; r < 16; ++r) acc += w[j][r] * zz[r];
                rj[j] = acc;
            }
            f32x4 res;
            res.x = rj[0]; res.y = rj[1]; res.z = rj[2]; res.w = rj[3];
            __builtin_nontemporal_store(res, (f32x4*)(op + (size_t)s * DOUT + o0));
        }
    }
}

// ---------------------------------------------------------------------------
extern "C" void kernel_launch(void* const* d_in, const int* in_sizes, int n_in,
                              void* d_out, int out_size, void* d_ws, size_t ws_size,
                              hipStream_t stream)
{
    const float* h      = (const float*)d_in[0];   // [B][S][DIN]   fp32
    const float* alpha  = (const float*)d_in[1];   // [B][K]        fp32
    const float* A_bank = (const float*)d_in[2];   // [K][R][DIN]   fp32
    const float* B_bank = (const float*)d_in[3];   // [K][DOUT][R]  fp32
    float* out = (float*)d_out;                    // [B][S][DOUT]  fp32

    // workspace layout (4 MiB total): z no longer materialized.
    float* Am = (float*)d_ws;                      // [B][R][DIN]  fp32, 2 MiB
    float* Bm = Am + BB * RR * DIN;                // [B][DOUT][R] fp32, 2 MiB

    mix_kernel<<<2048, 256, 0, stream>>>(alpha, A_bank, B_bank, Am, Bm);
    fused_kernel<<<dim3(128, 8), 256, 0, stream>>>(h, Am, Bm, out);
}